// Round 7
// baseline (135.435 us; speedup 1.0000x reference)
//
#include <hip/hip_runtime.h>

#define IN_F 1024
#define OUT_F 1024
#define NNZ 16384

typedef _Float16 f16;
typedef _Float16 f16x4 __attribute__((ext_vector_type(4)));
typedef _Float16 f16x8 __attribute__((ext_vector_type(8)));
typedef float f32x4 __attribute__((ext_vector_type(4)));
typedef unsigned short ushort8 __attribute__((ext_vector_type(8)));

#define AS1 __attribute__((address_space(1)))
#define AS3 __attribute__((address_space(3)))

// ---------------------------------------------------------------------------
// Workspace: S = staged W_eff (f16, 2 MiB) @0; mode flag @2MiB; Xs = staged
// f16 X @2MiB+4096 (64 MB; round-6 confirmed ws_size suffices).
//
// Staged layout v2 (quarter-grained, both S and Xs):
//   quarter qidx = (g*16 + kt)*2 + s : g = 128-row group, kt = 64-K tile,
//   s = K-half (32). Quarter = [128 rows][32 k] = 4096 f16, 512 slots x 16B.
//   slot u = r*4 + bb holds M[g*128+r][kt*64 + s*32 + ((bb^(r&3))<<3) .. +8].
// GEMM DMA-stages quarters linearly (global_load_lds) and reads with the same
// XOR -> conflict-free (8 lanes/bank-quad uniform, same distribution as the
// measured-0-conflict 64k layout), data correct (G21 both-sides rule).
// Logical k read by lane = kt*64 + S*32 + lk*8 + e  (identical to r2-r6).
// ---------------------------------------------------------------------------

__global__ void detect_mode(const unsigned short* __restrict__ w, int* __restrict__ mode) {
  __shared__ float smax[256];
  __shared__ int semax[256];
  int t = threadIdx.x;
  const float* wf = (const float*)w;
  float m32 = fabsf(wf[t]);
  m32 = fmaxf(m32, fabsf(wf[t + 256]));
  int e8 = 0;
#pragma unroll
  for (int j = 0; j < 8; ++j) {
    unsigned short u = w[t * 8 + j];
    int e = (u >> 7) & 0xFF;
    e8 = e > e8 ? e : e8;
  }
  smax[t] = m32; semax[t] = e8;
  __syncthreads();
  for (int s = 128; s > 0; s >>= 1) {
    if (t < s) {
      smax[t] = fmaxf(smax[t], smax[t + s]);
      semax[t] = semax[t] > semax[t + s] ? semax[t] : semax[t + s];
    }
    __syncthreads();
  }
  if (t == 0) {
    int m;
    if (!(smax[0] > 1e-6f)) m = 2;        // native f16
    else if (semax[0] >= 140) m = 0;      // f32 (upcast from fp16)
    else m = 1;                           // bf16
    *mode = m;
  }
}

__device__ __forceinline__ float load_w(const void* base, size_t i, int mode) {
  if (mode == 0) return ((const float*)base)[i];
  if (mode == 1) {
    unsigned int u = (unsigned int)((const unsigned short*)base)[i] << 16;
    return __uint_as_float(u);
  }
  return (float)((const f16*)base)[i];
}

__global__ void prep_base(const void* __restrict__ base, f16* __restrict__ S,
                          const int* __restrict__ modep) {
  int mode = *modep;
  int id = blockIdx.x * 256 + threadIdx.x;   // slot id, 131072 total
  int u = id & 511;
  int qidx = id >> 9;
  int kts = qidx & 31;
  int g = qidx >> 5;
  int r = u >> 2, bb = u & 3;
  int n = g * 128 + r;
  int k = (kts >> 1) * 64 + (kts & 1) * 32 + ((bb ^ (r & 3)) << 3);
  size_t off = (size_t)n * IN_F + k;
  f16x8 h;
  if (mode == 0) {
    const float* b = (const float*)base + off;
    float4 v0 = *reinterpret_cast<const float4*>(b);
    float4 v1 = *reinterpret_cast<const float4*>(b + 4);
    h = (f16x8){(f16)v0.x, (f16)v0.y, (f16)v0.z, (f16)v0.w,
                (f16)v1.x, (f16)v1.y, (f16)v1.z, (f16)v1.w};
  } else if (mode == 1) {
    ushort8 uv = *reinterpret_cast<const ushort8*>((const unsigned short*)base + off);
#pragma unroll
    for (int j = 0; j < 8; ++j)
      h[j] = (f16)__uint_as_float((unsigned int)uv[j] << 16);
  } else {
    h = *reinterpret_cast<const f16x8*>((const f16*)base + off);
  }
  *reinterpret_cast<f16x8*>(S + (size_t)id * 8) = h;
}

__global__ void prep_scatter(const void* __restrict__ base,
                             const void* __restrict__ vals,
                             const int* __restrict__ idx,
                             const float* __restrict__ alpha,
                             f16* __restrict__ S,
                             const int* __restrict__ modep) {
  int mode = *modep;
  int i = blockIdx.x * 256 + threadIdx.x;
  if (i >= NNZ) return;
  int id = idx[i];
  int n = id >> 10, k = id & 1023;
  float v = load_w(base, id, mode) + alpha[0] * load_w(vals, i, mode);
  int g = n >> 7, r = n & 127;
  int kt = k >> 6, kk = k & 63;
  int s = kk >> 5, b = (kk >> 3) & 3, e = kk & 7;
  int bb = b ^ (r & 3);
  size_t qidx = (size_t)(g * 16 + kt) * 2 + s;
  size_t pos = (qidx * 512 + (size_t)(r * 4 + bb)) * 8 + (size_t)e;
  S[pos] = (f16)v;
}

// Convert X (fp32, row-major) into staged quarter layout Xs. Grid-stride.
__global__ void __launch_bounds__(256) conv_x(const float* __restrict__ X,
                                              f16* __restrict__ Xs, int nslots) {
  int stride = gridDim.x * 256;
  for (int id = blockIdx.x * 256 + threadIdx.x; id < nslots; id += stride) {
    int u = id & 511;
    int qidx = id >> 9;
    int kts = qidx & 31;
    int g = qidx >> 5;
    int r = u >> 2, bb = u & 3;
    size_t row = (size_t)g * 128 + r;
    int k = (kts >> 1) * 64 + (kts & 1) * 32 + ((bb ^ (r & 3)) << 3);
    const float* p = X + row * IN_F + k;
    float4 v0 = *reinterpret_cast<const float4*>(p);
    float4 v1 = *reinterpret_cast<const float4*>(p + 4);
    f16x8 h = {(f16)v0.x, (f16)v0.y, (f16)v0.z, (f16)v0.w,
               (f16)v1.x, (f16)v1.y, (f16)v1.z, (f16)v1.w};
    *reinterpret_cast<f16x8*>(Xs + (size_t)id * 8) = h;
  }
}

#define SB0 __builtin_amdgcn_sched_barrier(0)
#define VMW(N) asm volatile("s_waitcnt vmcnt(" #N ")" ::: "memory")

// ---------------------------------------------------------------------------
// gemm3: counted-vmcnt 256x256 GEMM (m201-faithful). BK=64, 512 thr = 8 waves
// (2M x 4N), wave tile 128x64, LDS 128 KiB (2buf x 2 m-half x 2 k-half x
// [128][32] per operand). Per K-tile: 4 phases (Q,S) = (0,0),(1,0),(0,1),(1,1).
// k-half quarters of KT+1 issued at ph0 (k0, 4 loads) and ph2 (k1, 4 loads);
// waits: VMW(4) before the end-barriers of ph1 and ph3 ONLY (drains exactly
// the quarter read next, keeps 4 loads in flight). vmcnt hits 0 only in the
// prologue and at tile 15. Flight = ~3.5 phases >= HBM latency.
// ---------------------------------------------------------------------------

#define ISSUE_Q(SH, KT1, PB) do {                                              \
    _Pragma("unroll")                                                          \
    for (int h_ = 0; h_ < 2; ++h_) {                                           \
      __builtin_amdgcn_global_load_lds(                                        \
          (const AS1 void*)(Xs + ((size_t)(((2 * mt + h_) * 16 + (KT1)) * 2 + (SH))) * 4096 + t * 8), \
          (AS3 void*)(&sA[(((PB) * 2 + h_) * 2 + (SH)) * 4096 + t * 8]), 16, 0, 0); \
      __builtin_amdgcn_global_load_lds(                                        \
          (const AS1 void*)(Swz + ((size_t)(((nt * 2 + h_) * 16 + (KT1)) * 2 + (SH))) * 4096 + t * 8), \
          (AS3 void*)(&sB[(((PB) * 2 + h_) * 2 + (SH)) * 4096 + t * 8]), 16, 0, 0); \
    }                                                                          \
  } while (0)

#define PHASE3(P, Q, S_, LOADB, STG, ENDW) do {                                \
    int qbA_ = (((P) * 2 + wm) * 2 + (S_)) * 4096;                             \
    _Pragma("unroll")                                                          \
    for (int mf_ = 0; mf_ < 4; ++mf_) {                                        \
      int r_ = (Q) * 64 + mf_ * 16 + lr;                                       \
      afr[mf_] = *reinterpret_cast<const f16x8*>(                              \
          &sA[qbA_ + r_ * 32 + ((lk ^ (lr & 3)) << 3)]);                       \
    }                                                                          \
    if (LOADB) {                                                               \
      int qbB_ = (((P) * 2 + bh) * 2 + (S_)) * 4096;                           \
      _Pragma("unroll")                                                        \
      for (int nf_ = 0; nf_ < 4; ++nf_) {                                      \
        int r_ = bro + nf_ * 16 + lr;                                          \
        bfr[nf_] = *reinterpret_cast<const f16x8*>(                            \
            &sB[qbB_ + r_ * 32 + ((lk ^ (lr & 3)) << 3)]);                     \
      }                                                                        \
    }                                                                          \
    STG;                                                                       \
    SB0;                                                                       \
    __builtin_amdgcn_s_barrier();                                              \
    asm volatile("s_waitcnt lgkmcnt(0)" ::: "memory");                         \
    SB0;                                                                       \
    __builtin_amdgcn_s_setprio(1);                                             \
    _Pragma("unroll")                                                          \
    for (int mf_ = 0; mf_ < 4; ++mf_)                                          \
      _Pragma("unroll")                                                        \
      for (int nf_ = 0; nf_ < 4; ++nf_)                                        \
        acc[(Q) * 4 + mf_][nf_] = __builtin_amdgcn_mfma_f32_16x16x32_f16(      \
            afr[mf_], bfr[nf_], acc[(Q) * 4 + mf_][nf_], 0, 0, 0);             \
    __builtin_amdgcn_s_setprio(0);                                             \
    ENDW;                                                                      \
    SB0;                                                                       \
    __builtin_amdgcn_s_barrier();                                              \
    SB0;                                                                       \
  } while (0)

#define KTILE3(P, KT, PREF, LAST) do {                                         \
    PHASE3(P, 0, 0, true,  { if (PREF) ISSUE_Q(0, (KT) + 1, (P) ^ 1); }, {});  \
    PHASE3(P, 1, 0, false, {}, { if (LAST) { VMW(0); } else { VMW(4); } });    \
    PHASE3(P, 0, 1, true,  { if (PREF) ISSUE_Q(1, (KT) + 1, (P) ^ 1); }, {});  \
    PHASE3(P, 1, 1, false, {}, { VMW(4); });                                   \
  } while (0)

__global__ void __launch_bounds__(512, 2) gemm3(const f16* __restrict__ Xs,
                                                const f16* __restrict__ Swz,
                                                float* __restrict__ C) {
  extern __shared__ f16 lds[];
  f16* sA = lds;            // [2buf][2 m-half][2 k-half][4096]
  f16* sB = lds + 32768;

  int bidx = blockIdx.x;
  int q = gridDim.x >> 3;
  int wg = (bidx & 7) * q + (bidx >> 3);
  int mt = wg >> 2, nt = wg & 3;

  int t = threadIdx.x;
  int lane = t & 63;
  int w = t >> 6;
  int wm = w >> 2;           // M half (128 rows)
  int wn = w & 3;            // N quarter (64 cols)
  int lr = lane & 15;
  int lk = lane >> 4;
  int bh = wn >> 1;
  int bro = (wn & 1) * 64;

  f16x8 afr[4], bfr[4];
  f32x4 acc[8][4];
#pragma unroll
  for (int i = 0; i < 8; ++i)
#pragma unroll
    for (int j = 0; j < 4; ++j)
      acc[i][j] = (f32x4){0.f, 0.f, 0.f, 0.f};

  // prologue: fill buffer 0 with kt=0 (both k-halves), full drain once
  ISSUE_Q(0, 0, 0);
  ISSUE_Q(1, 0, 0);
  VMW(0);
  __builtin_amdgcn_s_barrier();
  SB0;

  for (int kt2 = 0; kt2 < 14; kt2 += 2) {
    KTILE3(0, kt2, true, false);
    KTILE3(1, kt2 + 1, true, false);
  }
  KTILE3(0, 14, true, false);
  KTILE3(1, 15, false, true);

  float* Cw = C + (size_t)(mt * 256 + wm * 128 + lk * 4) * OUT_F + nt * 256 + wn * 64 + lr;
#pragma unroll
  for (int m = 0; m < 8; ++m) {
    int rowo = (m >> 2) * 64 + (m & 3) * 16;
#pragma unroll
    for (int nf = 0; nf < 4; ++nf)
#pragma unroll
      for (int g = 0; g < 4; ++g)
        Cw[(size_t)(rowo + g) * OUT_F + nf * 16] = acc[m][nf][g];
  }
}

extern "C" void kernel_launch(void* const* d_in, const int* in_sizes, int n_in,
                              void* d_out, int out_size, void* d_ws, size_t ws_size,
                              hipStream_t stream) {
  const float* X = (const float*)d_in[0];
  const void* base = d_in[1];
  const void* vals = d_in[2];
  const int* idx = (const int*)d_in[3];
  const float* alpha = (const float*)d_in[4];
  float* out = (float*)d_out;
  f16* S = (f16*)d_ws;
  int* modep = (int*)((char*)d_ws + 2 * 1024 * 1024);
  f16* Xs = (f16*)((char*)d_ws + 2 * 1024 * 1024 + 4096);

  int M = in_sizes[0] / IN_F;              // 32768
  int nslots = (M * IN_F) / 8;             // 4,194,304

  (void)hipFuncSetAttribute(reinterpret_cast<const void*>(&gemm3),
                            hipFuncAttributeMaxDynamicSharedMemorySize, 131072);

  detect_mode<<<dim3(1), dim3(256), 0, stream>>>((const unsigned short*)base, modep);
  prep_base<<<dim3(512), dim3(256), 0, stream>>>(base, S, modep);
  prep_scatter<<<dim3((NNZ + 255) / 256), dim3(256), 0, stream>>>(base, vals, idx, alpha, S, modep);
  conv_x<<<dim3(2048), dim3(256), 0, stream>>>(X, Xs, nslots);
  gemm3<<<dim3((M / 256) * 4), dim3(512), 131072, stream>>>(Xs, S, out);
}

// Round 8
// 128.635 us; speedup vs baseline: 1.0529x; 1.0529x over previous
//
#include <hip/hip_runtime.h>

#define IN_F 1024
#define OUT_F 1024
#define NNZ 16384

typedef _Float16 f16;
typedef _Float16 f16x4 __attribute__((ext_vector_type(4)));
typedef _Float16 f16x8 __attribute__((ext_vector_type(8)));
typedef float f32x4 __attribute__((ext_vector_type(4)));
typedef unsigned short ushort8 __attribute__((ext_vector_type(8)));

#define AS1 __attribute__((address_space(1)))
#define AS3 __attribute__((address_space(3)))

// ---------------------------------------------------------------------------
// Workspace: S = staged W_eff (f16, 2 MiB) @0; mode flag @2MiB; Xs @2MiB+4096.
//
// Staged layout v3 (row-half quarters, both S and Xs):
//   quarter qidx = g2*16 + kt : g2 = 64-row group, kt = 64-K tile.
//   Quarter = [64 rows][64 k] = 4096 f16 = 512 slots x 16B.
//   slot u = r*8 + bb holds M[g2*64+r][kt*64 + ((bb^(r&7))<<3) .. +8].
// This is the PROVEN 128B-row-stride + 8-way-XOR layout (0 bank conflicts,
// rounds 2-6), at quarter granularity so the GEMM can keep counted vmcnt.
// ---------------------------------------------------------------------------

__global__ void detect_mode(const unsigned short* __restrict__ w, int* __restrict__ mode) {
  __shared__ float smax[256];
  __shared__ int semax[256];
  int t = threadIdx.x;
  const float* wf = (const float*)w;
  float m32 = fabsf(wf[t]);
  m32 = fmaxf(m32, fabsf(wf[t + 256]));
  int e8 = 0;
#pragma unroll
  for (int j = 0; j < 8; ++j) {
    unsigned short u = w[t * 8 + j];
    int e = (u >> 7) & 0xFF;
    e8 = e > e8 ? e : e8;
  }
  smax[t] = m32; semax[t] = e8;
  __syncthreads();
  for (int s = 128; s > 0; s >>= 1) {
    if (t < s) {
      smax[t] = fmaxf(smax[t], smax[t + s]);
      semax[t] = semax[t] > semax[t + s] ? semax[t] : semax[t + s];
    }
    __syncthreads();
  }
  if (t == 0) {
    int m;
    if (!(smax[0] > 1e-6f)) m = 2;        // native f16
    else if (semax[0] >= 140) m = 0;      // f32 (upcast from fp16)
    else m = 1;                           // bf16
    *mode = m;
  }
}

__device__ __forceinline__ float load_w(const void* base, size_t i, int mode) {
  if (mode == 0) return ((const float*)base)[i];
  if (mode == 1) {
    unsigned int u = (unsigned int)((const unsigned short*)base)[i] << 16;
    return __uint_as_float(u);
  }
  return (float)((const f16*)base)[i];
}

__global__ void prep_base(const void* __restrict__ base, f16* __restrict__ S,
                          const int* __restrict__ modep) {
  int mode = *modep;
  int id = blockIdx.x * 256 + threadIdx.x;   // slot id, 131072 total
  int u = id & 511;
  int qidx = id >> 9;                        // 256 quarters
  int kt = qidx & 15;
  int g2 = qidx >> 4;
  int r = u >> 3, bb = u & 7;
  int n = g2 * 64 + r;
  int k = kt * 64 + ((bb ^ (r & 7)) << 3);
  size_t off = (size_t)n * IN_F + k;
  f16x8 h;
  if (mode == 0) {
    const float* b = (const float*)base + off;
    float4 v0 = *reinterpret_cast<const float4*>(b);
    float4 v1 = *reinterpret_cast<const float4*>(b + 4);
    h = (f16x8){(f16)v0.x, (f16)v0.y, (f16)v0.z, (f16)v0.w,
                (f16)v1.x, (f16)v1.y, (f16)v1.z, (f16)v1.w};
  } else if (mode == 1) {
    ushort8 uv = *reinterpret_cast<const ushort8*>((const unsigned short*)base + off);
#pragma unroll
    for (int j = 0; j < 8; ++j)
      h[j] = (f16)__uint_as_float((unsigned int)uv[j] << 16);
  } else {
    h = *reinterpret_cast<const f16x8*>((const f16*)base + off);
  }
  *reinterpret_cast<f16x8*>(S + (size_t)id * 8) = h;
}

__global__ void prep_scatter(const void* __restrict__ base,
                             const void* __restrict__ vals,
                             const int* __restrict__ idx,
                             const float* __restrict__ alpha,
                             f16* __restrict__ S,
                             const int* __restrict__ modep) {
  int mode = *modep;
  int i = blockIdx.x * 256 + threadIdx.x;
  if (i >= NNZ) return;
  int id = idx[i];
  int n = id >> 10, k = id & 1023;
  float v = load_w(base, id, mode) + alpha[0] * load_w(vals, i, mode);
  int g2 = n >> 6, r = n & 63;
  int kt = k >> 6, kk = k & 63;
  int b = kk >> 3, e = kk & 7;
  int bb = b ^ (r & 7);
  size_t pos = (((size_t)(g2 * 16 + kt)) * 512 + (size_t)(r * 8 + bb)) * 8 + (size_t)e;
  S[pos] = (f16)v;
}

// Convert X (fp32 row-major) -> staged quarter layout Xs. Coalesced:
// thread unit = one 8-f16 chunk; loads contiguous, stores 128B-contiguous.
__global__ void __launch_bounds__(256) conv_x(const float* __restrict__ X,
                                              f16* __restrict__ Xs, int total) {
  int stride = gridDim.x * 256;
  for (int id = blockIdx.x * 256 + threadIdx.x; id < total; id += stride) {
    int kc = id & 127;                 // 8-f16 chunk within row
    size_t row = (size_t)(id >> 7);
    int kt = kc >> 3, b = kc & 7;
    int g2 = (int)(row >> 6), r = (int)(row & 63);
    int bb = b ^ (r & 7);
    const float* p = X + row * IN_F + kc * 8;
    float4 v0 = *reinterpret_cast<const float4*>(p);
    float4 v1 = *reinterpret_cast<const float4*>(p + 4);
    f16x8 h = {(f16)v0.x, (f16)v0.y, (f16)v0.z, (f16)v0.w,
               (f16)v1.x, (f16)v1.y, (f16)v1.z, (f16)v1.w};
    *reinterpret_cast<f16x8*>(Xs + (((size_t)(g2 * 16 + kt)) * 512 + (size_t)(r * 8 + bb)) * 8) = h;
  }
}

#define SB0 __builtin_amdgcn_sched_barrier(0)
#define VMW(N) asm volatile("s_waitcnt vmcnt(" #N ")" ::: "memory")

// ---------------------------------------------------------------------------
// gemm4: 256x256, BK=64, 512 thr (8 waves 2Mx4N), wave tile 128x64.
// LDS 128 KiB: sA/sB = [2buf][4 row-quarters][64][64] f16 (proven swizzle).
// Phases (Q,S): (0,0),(1,0),(0,1),(1,1). Phase (Q,S) reads A row-quarters
// {wm*2+Q} and B row-quarter wn (S selects columns only).
// Prefetch of KT+1 into buffer P^1: ph0: B x4; ph1: A q0,q2; ph2: A q1,q3.
// Waits: VMW(4) at ph0-end (drains A q1,q3 of CURRENT tile, keeps new B),
// VMW(2) at ph3-end (drains B+Aq02 of next tile, keeps its Aq13).
// vmcnt reaches 0 only in prologue and tile 15. Flight ~4 phases.
// ---------------------------------------------------------------------------

#define ISSUE_QA(QI, KT1, PB)                                                  \
    __builtin_amdgcn_global_load_lds(                                          \
        (const AS1 void*)(Xs + ((size_t)((mt * 4 + (QI)) * 16 + (KT1))) * 4096 + t * 8), \
        (AS3 void*)(&sA[((PB) * 4 + (QI)) * 4096 + t * 8]), 16, 0, 0)

#define ISSUE_QB(QI, KT1, PB)                                                  \
    __builtin_amdgcn_global_load_lds(                                          \
        (const AS1 void*)(Swz + ((size_t)((nt * 4 + (QI)) * 16 + (KT1))) * 4096 + t * 8), \
        (AS3 void*)(&sB[((PB) * 4 + (QI)) * 4096 + t * 8]), 16, 0, 0)

#define PHASE4(P, Q, S_, LOADB, STG, ENDW) do {                                \
    int qa_ = ((P) * 4 + wm * 2 + (Q)) * 4096;                                 \
    _Pragma("unroll")                                                          \
    for (int mf_ = 0; mf_ < 4; ++mf_) {                                        \
      int r_ = mf_ * 16 + lr;                                                  \
      int blk_ = ((S_) * 4 + lk) ^ (lr & 7);                                   \
      afr[mf_] = *reinterpret_cast<const f16x8*>(&sA[qa_ + r_ * 64 + blk_ * 8]); \
    }                                                                          \
    if (LOADB) {                                                               \
      int qb_ = ((P) * 4 + wn) * 4096;                                         \
      _Pragma("unroll")                                                        \
      for (int nf_ = 0; nf_ < 4; ++nf_) {                                      \
        int r_ = nf_ * 16 + lr;                                                \
        int blk_ = ((S_) * 4 + lk) ^ (lr & 7);                                 \
        bfr[nf_] = *reinterpret_cast<const f16x8*>(&sB[qb_ + r_ * 64 + blk_ * 8]); \
      }                                                                        \
    }                                                                          \
    STG;                                                                       \
    SB0;                                                                       \
    __builtin_amdgcn_s_barrier();                                              \
    asm volatile("s_waitcnt lgkmcnt(0)" ::: "memory");                         \
    SB0;                                                                       \
    __builtin_amdgcn_s_setprio(1);                                             \
    _Pragma("unroll")                                                          \
    for (int mf_ = 0; mf_ < 4; ++mf_)                                          \
      _Pragma("unroll")                                                        \
      for (int nf_ = 0; nf_ < 4; ++nf_)                                        \
        acc[(Q) * 4 + mf_][nf_] = __builtin_amdgcn_mfma_f32_16x16x32_f16(      \
            afr[mf_], bfr[nf_], acc[(Q) * 4 + mf_][nf_], 0, 0, 0);             \
    __builtin_amdgcn_s_setprio(0);                                             \
    ENDW;                                                                      \
    SB0;                                                                       \
    __builtin_amdgcn_s_barrier();                                              \
    SB0;                                                                       \
  } while (0)

#define KTILE4(P, KT, PREF, LAST) do {                                         \
    PHASE4(P, 0, 0, true,                                                      \
           { if (PREF) { ISSUE_QB(0, (KT) + 1, (P) ^ 1); ISSUE_QB(1, (KT) + 1, (P) ^ 1); \
                         ISSUE_QB(2, (KT) + 1, (P) ^ 1); ISSUE_QB(3, (KT) + 1, (P) ^ 1); } }, \
           { if (LAST) { VMW(0); } else { VMW(4); } });                        \
    PHASE4(P, 1, 0, false,                                                     \
           { if (PREF) { ISSUE_QA(0, (KT) + 1, (P) ^ 1); ISSUE_QA(2, (KT) + 1, (P) ^ 1); } }, \
           {});                                                                \
    PHASE4(P, 0, 1, true,                                                      \
           { if (PREF) { ISSUE_QA(1, (KT) + 1, (P) ^ 1); ISSUE_QA(3, (KT) + 1, (P) ^ 1); } }, \
           {});                                                                \
    PHASE4(P, 1, 1, false, {}, { VMW(2); });                                   \
  } while (0)

__global__ void __launch_bounds__(512, 2) gemm4(const f16* __restrict__ Xs,
                                                const f16* __restrict__ Swz,
                                                float* __restrict__ C) {
  extern __shared__ f16 lds[];
  f16* sA = lds;            // [2buf][4 quarters][4096]
  f16* sB = lds + 32768;

  int bidx = blockIdx.x;
  int q = gridDim.x >> 3;
  int wg = (bidx & 7) * q + (bidx >> 3);
  int mt = wg >> 2, nt = wg & 3;

  int t = threadIdx.x;
  int lane = t & 63;
  int w = t >> 6;
  int wm = w >> 2;           // M half (128 rows)
  int wn = w & 3;            // N quarter (64 cols) == B row-quarter
  int lr = lane & 15;
  int lk = lane >> 4;

  f16x8 afr[4], bfr[4];
  f32x4 acc[8][4];
#pragma unroll
  for (int i = 0; i < 8; ++i)
#pragma unroll
    for (int j = 0; j < 4; ++j)
      acc[i][j] = (f32x4){0.f, 0.f, 0.f, 0.f};

  // prologue: fill buffer 0 with kt=0 (all 8 quarters), full drain once
  ISSUE_QB(0, 0, 0); ISSUE_QB(1, 0, 0); ISSUE_QB(2, 0, 0); ISSUE_QB(3, 0, 0);
  ISSUE_QA(0, 0, 0); ISSUE_QA(1, 0, 0); ISSUE_QA(2, 0, 0); ISSUE_QA(3, 0, 0);
  VMW(0);
  __builtin_amdgcn_s_barrier();
  SB0;

  for (int kt2 = 0; kt2 < 14; kt2 += 2) {
    KTILE4(0, kt2, true, false);
    KTILE4(1, kt2 + 1, true, false);
  }
  KTILE4(0, 14, true, false);
  KTILE4(1, 15, false, true);

  float* Cw = C + (size_t)(mt * 256 + wm * 128 + lk * 4) * OUT_F + nt * 256 + wn * 64 + lr;
#pragma unroll
  for (int m = 0; m < 8; ++m) {
    int rowo = (m >> 2) * 64 + (m & 3) * 16;
#pragma unroll
    for (int nf = 0; nf < 4; ++nf)
#pragma unroll
      for (int g = 0; g < 4; ++g)
        Cw[(size_t)(rowo + g) * OUT_F + nf * 16] = acc[m][nf][g];
  }
}

extern "C" void kernel_launch(void* const* d_in, const int* in_sizes, int n_in,
                              void* d_out, int out_size, void* d_ws, size_t ws_size,
                              hipStream_t stream) {
  const float* X = (const float*)d_in[0];
  const void* base = d_in[1];
  const void* vals = d_in[2];
  const int* idx = (const int*)d_in[3];
  const float* alpha = (const float*)d_in[4];
  float* out = (float*)d_out;
  f16* S = (f16*)d_ws;
  int* modep = (int*)((char*)d_ws + 2 * 1024 * 1024);
  f16* Xs = (f16*)((char*)d_ws + 2 * 1024 * 1024 + 4096);

  int M = in_sizes[0] / IN_F;              // 32768
  int total = (M * IN_F) / 8;              // 8-f16 chunks

  (void)hipFuncSetAttribute(reinterpret_cast<const void*>(&gemm4),
                            hipFuncAttributeMaxDynamicSharedMemorySize, 131072);

  detect_mode<<<dim3(1), dim3(256), 0, stream>>>((const unsigned short*)base, modep);
  prep_base<<<dim3(512), dim3(256), 0, stream>>>(base, S, modep);
  prep_scatter<<<dim3((NNZ + 255) / 256), dim3(256), 0, stream>>>(base, vals, idx, alpha, S, modep);
  conv_x<<<dim3(2048), dim3(256), 0, stream>>>(X, Xs, total);
  gemm4<<<dim3((M / 256) * 4), dim3(512), 131072, stream>>>(Xs, S, out);
}

// Round 10
// 127.722 us; speedup vs baseline: 1.0604x; 1.0071x over previous
//
#include <hip/hip_runtime.h>

#define IN_F 1024
#define OUT_F 1024
#define NNZ 16384

typedef _Float16 f16;
typedef _Float16 f16x4 __attribute__((ext_vector_type(4)));
typedef _Float16 f16x8 __attribute__((ext_vector_type(8)));
typedef float f32x4 __attribute__((ext_vector_type(4)));
typedef unsigned short ushort8 __attribute__((ext_vector_type(8)));

#define AS1 __attribute__((address_space(1)))
#define AS3 __attribute__((address_space(3)))

// ---------------------------------------------------------------------------
// Workspace: S = staged W_eff (f16, 2 MiB) @0; mode flag @2MiB; Xs @2MiB+4096.
// Staged layout (quarters, both S and Xs): quarter qidx = g2*16 + kt
// (g2 = 64-row group, kt = 64-K tile) = [64 rows][64 k] = 512 slots x 16B;
// slot u = r*8 + bb holds M[g2*64+r][kt*64 + ((bb^(r&7))<<3) .. +8].
// Proven 128B-row-stride + 8-way-XOR layout (0 bank conflicts, r8 measured).
//
// SYNC INVARIANT (r9 lesson): a DMA-staged LDS buffer is written by ALL
// waves; vmcnt only drains the issuing wave's loads. Therefore every
// cross-wave read of a staged buffer must be preceded by VMW(n) -> s_barrier.
// ---------------------------------------------------------------------------

__global__ void detect_mode(const unsigned short* __restrict__ w, int* __restrict__ mode) {
  __shared__ float smax[256];
  __shared__ int semax[256];
  int t = threadIdx.x;
  const float* wf = (const float*)w;
  float m32 = fabsf(wf[t]);
  m32 = fmaxf(m32, fabsf(wf[t + 256]));
  int e8 = 0;
#pragma unroll
  for (int j = 0; j < 8; ++j) {
    unsigned short u = w[t * 8 + j];
    int e = (u >> 7) & 0xFF;
    e8 = e > e8 ? e : e8;
  }
  smax[t] = m32; semax[t] = e8;
  __syncthreads();
  for (int s = 128; s > 0; s >>= 1) {
    if (t < s) {
      smax[t] = fmaxf(smax[t], smax[t + s]);
      semax[t] = semax[t] > semax[t + s] ? semax[t] : semax[t + s];
    }
    __syncthreads();
  }
  if (t == 0) {
    int m;
    if (!(smax[0] > 1e-6f)) m = 2;        // native f16
    else if (semax[0] >= 140) m = 0;      // f32 (upcast from fp16)
    else m = 1;                           // bf16
    *mode = m;
  }
}

__device__ __forceinline__ float load_w(const void* base, size_t i, int mode) {
  if (mode == 0) return ((const float*)base)[i];
  if (mode == 1) {
    unsigned int u = (unsigned int)((const unsigned short*)base)[i] << 16;
    return __uint_as_float(u);
  }
  return (float)((const f16*)base)[i];
}

__global__ void prep_base(const void* __restrict__ base, f16* __restrict__ S,
                          const int* __restrict__ modep) {
  int mode = *modep;
  int id = blockIdx.x * 256 + threadIdx.x;   // slot id, 131072 total
  int u = id & 511;
  int qidx = id >> 9;                        // 256 quarters
  int kt = qidx & 15;
  int g2 = qidx >> 4;
  int r = u >> 3, bb = u & 7;
  int n = g2 * 64 + r;
  int k = kt * 64 + ((bb ^ (r & 7)) << 3);
  size_t off = (size_t)n * IN_F + k;
  f16x8 h;
  if (mode == 0) {
    const float* b = (const float*)base + off;
    float4 v0 = *reinterpret_cast<const float4*>(b);
    float4 v1 = *reinterpret_cast<const float4*>(b + 4);
    h = (f16x8){(f16)v0.x, (f16)v0.y, (f16)v0.z, (f16)v0.w,
                (f16)v1.x, (f16)v1.y, (f16)v1.z, (f16)v1.w};
  } else if (mode == 1) {
    ushort8 uv = *reinterpret_cast<const ushort8*>((const unsigned short*)base + off);
#pragma unroll
    for (int j = 0; j < 8; ++j)
      h[j] = (f16)__uint_as_float((unsigned int)uv[j] << 16);
  } else {
    h = *reinterpret_cast<const f16x8*>((const f16*)base + off);
  }
  *reinterpret_cast<f16x8*>(S + (size_t)id * 8) = h;
}

__global__ void prep_scatter(const void* __restrict__ base,
                             const void* __restrict__ vals,
                             const int* __restrict__ idx,
                             const float* __restrict__ alpha,
                             f16* __restrict__ S,
                             const int* __restrict__ modep) {
  int mode = *modep;
  int i = blockIdx.x * 256 + threadIdx.x;
  if (i >= NNZ) return;
  int id = idx[i];
  int n = id >> 10, k = id & 1023;
  float v = load_w(base, id, mode) + alpha[0] * load_w(vals, i, mode);
  int g2 = n >> 6, r = n & 63;
  int kt = k >> 6, kk = k & 63;
  int b = kk >> 3, e = kk & 7;
  int bb = b ^ (r & 7);
  size_t pos = (((size_t)(g2 * 16 + kt)) * 512 + (size_t)(r * 8 + bb)) * 8 + (size_t)e;
  S[pos] = (f16)v;
}

// conv_x: thread unit = one staged 16B slot -> stores fully contiguous
// (1 KiB per wave); loads are 32B pieces permuted within a 256B row segment.
__global__ void __launch_bounds__(256) conv_x(const float* __restrict__ X,
                                              f16* __restrict__ Xs, int total) {
  int stride = gridDim.x * 256;
  for (int id = blockIdx.x * 256 + threadIdx.x; id < total; id += stride) {
    int u = id & 511;
    int qidx = id >> 9;
    int kt = qidx & 15;
    int g2 = qidx >> 4;
    int r = u >> 3, bb = u & 7;
    int b = bb ^ (r & 7);
    size_t row = (size_t)g2 * 64 + r;
    const float* p = X + row * IN_F + kt * 64 + b * 8;
    float4 v0 = *reinterpret_cast<const float4*>(p);
    float4 v1 = *reinterpret_cast<const float4*>(p + 4);
    f16x8 h = {(f16)v0.x, (f16)v0.y, (f16)v0.z, (f16)v0.w,
               (f16)v1.x, (f16)v1.y, (f16)v1.z, (f16)v1.w};
    *reinterpret_cast<f16x8*>(Xs + (size_t)id * 8) = h;   // contiguous
  }
}

#define SB0 __builtin_amdgcn_sched_barrier(0)
#define VMW(N) asm volatile("s_waitcnt vmcnt(" #N ")" ::: "memory")

// ---------------------------------------------------------------------------
// gemm5b: 256x256, BK=64, 512 thr (8 waves 2Mx4N), wave tile 128x64.
// LDS 128 KiB: sA/sB = [2buf][4 row-quarters][64][64] f16 (proven swizzle).
// Fat phases, race-free: 2 barriers per K-tile.
// ph0: [issue QA(KT+1)x4] -> VMW(4) -> s_barrier (RAW gate: buf P resident)
//      -> ds_read S0 (12xb128) -> [issue QB(KT+1)x4] -> lgkm(0) -> 32 MFMA.
// ph1: ds_read S1 -> lgkm(0) -> 32 MFMA -> s_barrier (WAR gate: reads of P
//      done before next tile's DMAs overwrite it).
// vmcnt never 0 in main loop (VMW(4) keeps QA(KT+1) in flight across the
// barrier); VMW(0) only in prologue and final tile.
// ---------------------------------------------------------------------------

#define ISSUE_QA(QI, KT1, PB)                                                  \
    __builtin_amdgcn_global_load_lds(                                          \
        (const AS1 void*)(Xs + ((size_t)((mt * 4 + (QI)) * 16 + (KT1))) * 4096 + t * 8), \
        (AS3 void*)(&sA[((PB) * 4 + (QI)) * 4096 + t * 8]), 16, 0, 0)

#define ISSUE_QB(QI, KT1, PB)                                                  \
    __builtin_amdgcn_global_load_lds(                                          \
        (const AS1 void*)(Swz + ((size_t)((nt * 4 + (QI)) * 16 + (KT1))) * 4096 + t * 8), \
        (AS3 void*)(&sB[((PB) * 4 + (QI)) * 4096 + t * 8]), 16, 0, 0)

#define DSREAD(P, S_) do {                                                     \
    int blk_;                                                                  \
    _Pragma("unroll")                                                          \
    for (int qq_ = 0; qq_ < 2; ++qq_) {                                        \
      int qa_ = ((P) * 4 + wm * 2 + qq_) * 4096;                               \
      _Pragma("unroll")                                                        \
      for (int mf_ = 0; mf_ < 4; ++mf_) {                                      \
        int r_ = mf_ * 16 + lr;                                                \
        blk_ = ((S_) * 4 + lk) ^ (lr & 7);                                     \
        afr[qq_][mf_] = *reinterpret_cast<const f16x8*>(&sA[qa_ + r_ * 64 + blk_ * 8]); \
      }                                                                        \
    }                                                                          \
    int qb_ = ((P) * 4 + wn) * 4096;                                           \
    _Pragma("unroll")                                                          \
    for (int nf_ = 0; nf_ < 4; ++nf_) {                                        \
      int r_ = nf_ * 16 + lr;                                                  \
      blk_ = ((S_) * 4 + lk) ^ (lr & 7);                                       \
      bfr[nf_] = *reinterpret_cast<const f16x8*>(&sB[qb_ + r_ * 64 + blk_ * 8]); \
    }                                                                          \
  } while (0)

#define MFMA32(S_) do {                                                        \
    asm volatile("s_waitcnt lgkmcnt(0)" ::: "memory");                         \
    SB0;                                                                       \
    __builtin_amdgcn_s_setprio(1);                                             \
    _Pragma("unroll")                                                          \
    for (int qq_ = 0; qq_ < 2; ++qq_)                                          \
      _Pragma("unroll")                                                        \
      for (int mf_ = 0; mf_ < 4; ++mf_)                                        \
        _Pragma("unroll")                                                      \
        for (int nf_ = 0; nf_ < 4; ++nf_)                                      \
          acc[qq_ * 4 + mf_][nf_] = __builtin_amdgcn_mfma_f32_16x16x32_f16(    \
              afr[qq_][mf_], bfr[nf_], acc[qq_ * 4 + mf_][nf_], 0, 0, 0);      \
    __builtin_amdgcn_s_setprio(0);                                             \
  } while (0)

#define KTILE5(P, KT, PREF) do {                                               \
    /* ---- ph0 (S=0) ---- */                                                  \
    if (PREF) { ISSUE_QA(0, (KT) + 1, (P) ^ 1); ISSUE_QA(1, (KT) + 1, (P) ^ 1);\
                ISSUE_QA(2, (KT) + 1, (P) ^ 1); ISSUE_QA(3, (KT) + 1, (P) ^ 1);\
                SB0; VMW(4); }                                                 \
    else { VMW(0); }                                                           \
    SB0;                                                                       \
    __builtin_amdgcn_s_barrier();   /* RAW gate: buffer P fully resident */    \
    SB0;                                                                       \
    DSREAD(P, 0);                                                              \
    if (PREF) { SB0; ISSUE_QB(0, (KT) + 1, (P) ^ 1); ISSUE_QB(1, (KT) + 1, (P) ^ 1);\
                ISSUE_QB(2, (KT) + 1, (P) ^ 1); ISSUE_QB(3, (KT) + 1, (P) ^ 1); } \
    MFMA32(0);                                                                 \
    /* ---- ph1 (S=1) ---- */                                                  \
    DSREAD(P, 1);                                                              \
    MFMA32(1);                                                                 \
    SB0;                                                                       \
    __builtin_amdgcn_s_barrier();   /* WAR gate: reads of P complete */        \
    SB0;                                                                       \
  } while (0)

__global__ void __launch_bounds__(512, 2) gemm5(const f16* __restrict__ Xs,
                                                const f16* __restrict__ Swz,
                                                float* __restrict__ C) {
  extern __shared__ f16 lds[];
  f16* sA = lds;            // [2buf][4 quarters][4096]
  f16* sB = lds + 32768;

  int bidx = blockIdx.x;
  int q = gridDim.x >> 3;
  int wg = (bidx & 7) * q + (bidx >> 3);
  int mt = wg >> 2, nt = wg & 3;

  int t = threadIdx.x;
  int lane = t & 63;
  int w = t >> 6;
  int wm = w >> 2;           // M half (128 rows) -> A quarters 2wm, 2wm+1
  int wn = w & 3;            // N quarter (64 cols) == B row-quarter
  int lr = lane & 15;
  int lk = lane >> 4;

  f16x8 afr[2][4], bfr[4];
  f32x4 acc[8][4];
#pragma unroll
  for (int i = 0; i < 8; ++i)
#pragma unroll
    for (int j = 0; j < 4; ++j)
      acc[i][j] = (f32x4){0.f, 0.f, 0.f, 0.f};

  // prologue: fill buffer 0 with kt=0 (all 8 quarters), full drain + barrier
  ISSUE_QA(0, 0, 0); ISSUE_QA(1, 0, 0); ISSUE_QA(2, 0, 0); ISSUE_QA(3, 0, 0);
  ISSUE_QB(0, 0, 0); ISSUE_QB(1, 0, 0); ISSUE_QB(2, 0, 0); ISSUE_QB(3, 0, 0);
  VMW(0);
  __builtin_amdgcn_s_barrier();
  SB0;

  for (int kt2 = 0; kt2 < 14; kt2 += 2) {
    KTILE5(0, kt2, true);
    KTILE5(1, kt2 + 1, true);
  }
  KTILE5(0, 14, true);
  KTILE5(1, 15, false);

  float* Cw = C + (size_t)(mt * 256 + wm * 128 + lk * 4) * OUT_F + nt * 256 + wn * 64 + lr;
#pragma unroll
  for (int m = 0; m < 8; ++m) {
    int rowo = (m >> 2) * 64 + (m & 3) * 16;
#pragma unroll
    for (int nf = 0; nf < 4; ++nf)
#pragma unroll
      for (int g = 0; g < 4; ++g)
        Cw[(size_t)(rowo + g) * OUT_F + nf * 16] = acc[m][nf][g];
  }
}

extern "C" void kernel_launch(void* const* d_in, const int* in_sizes, int n_in,
                              void* d_out, int out_size, void* d_ws, size_t ws_size,
                              hipStream_t stream) {
  const float* X = (const float*)d_in[0];
  const void* base = d_in[1];
  const void* vals = d_in[2];
  const int* idx = (const int*)d_in[3];
  const float* alpha = (const float*)d_in[4];
  float* out = (float*)d_out;
  f16* S = (f16*)d_ws;
  int* modep = (int*)((char*)d_ws + 2 * 1024 * 1024);
  f16* Xs = (f16*)((char*)d_ws + 2 * 1024 * 1024 + 4096);

  int M = in_sizes[0] / IN_F;              // 32768
  int total = (M * IN_F) / 8;              // staged 16B slots

  (void)hipFuncSetAttribute(reinterpret_cast<const void*>(&gemm5),
                            hipFuncAttributeMaxDynamicSharedMemorySize, 131072);

  detect_mode<<<dim3(1), dim3(256), 0, stream>>>((const unsigned short*)base, modep);
  prep_base<<<dim3(512), dim3(256), 0, stream>>>(base, S, modep);
  prep_scatter<<<dim3((NNZ + 255) / 256), dim3(256), 0, stream>>>(base, vals, idx, alpha, S, modep);
  conv_x<<<dim3(2048), dim3(256), 0, stream>>>(X, Xs, total);
  gemm5<<<dim3((M / 256) * 4), dim3(512), 131072, stream>>>(Xs, S, out);
}